// Round 6
// baseline (343.863 us; speedup 1.0000x reference)
//
#include <hip/hip_runtime.h>
#include <hip/hip_bf16.h>

// SimpleVSN: B=64, T=512, F=32, H=64. Inputs fp32, output fp32.
//
// Algebra: never materialize v.
//   U[f,hh,fp] = sum_k W2[f,hh,k]*Wsel[fp, f*64+k]   (device-global, 256KB)
//   c[fp]      = bsel[fp] + sum_d b2flat[d]*Wsel[fp,d]
//   logits[fp] = sum_{f,hh} h[f,hh]*U[f,hh,fp] + c[fp]
//   out[k]     = sum_f w_f * (h_f @ W2[f] + b2[f])   (h recomputed, cheap)
//
// vsn_main (v2): 512 threads = 8 waves; lane = token (64 tok/block);
// each wave owns 4 features -> per-wave work halved, 16 waves/CU (vs 8).
// Cross-wave reduction via LDS atomicAdd (ds_add_f32) into padded buffers:
//   lacc[tok][j] stride 33 -> banks (lane+j)%32, conflict-free
//   oacc[tok][k] stride 65 -> banks (lane+k)%32, conflict-free
// All weight addresses wave-uniform (readfirstlane'd fbase) -> s_load.

namespace {
constexpr int F = 32;
constexpr int H = 64;
constexpr int TOK_PER_BLK = 64;
constexpr int WAVES = 8;
constexpr int FPW = F / WAVES;   // 4 features per wave
}

__device__ float g_U[F * H * F];   // [f][hh][fp]
__device__ float g_c[F];

// One block per feature f (blocks 0..31): U[f] = W2[f] @ Wsel_sub^T via LDS.
// Block 32: c[fp].
__global__ void __launch_bounds__(256)
vsn_pre(const float* __restrict__ W2, const float* __restrict__ b2,
        const float* __restrict__ Wsel, const float* __restrict__ bsel) {
  __shared__ float sW2[H * H];        // [hh][k]
  __shared__ float sSel[F * 65];      // [fp][k], padded: bank (fp+k)%32
  const int f = blockIdx.x;
  const int t = threadIdx.x;
  if (f < F) {
    #pragma unroll
    for (int i = 0; i < 16; ++i)      // 4096 floats, coalesced
      sW2[t + 256 * i] = W2[f * (H * H) + t + 256 * i];
    const int kk = t & 63;            // coalesced row loads of Wsel slice
    #pragma unroll
    for (int r = 0; r < 8; ++r) {
      int fp = (t >> 6) + 4 * r;      // 4 rows per pass
      sSel[fp * 65 + kk] = Wsel[fp * (F * H) + f * H + kk];
    }
    __syncthreads();
    const int fp = t & 31;
    const int hh0 = t >> 5;           // 0..7
    #pragma unroll
    for (int i = 0; i < 8; ++i) {
      int hh = hh0 * 8 + i;
      float s = 0.f;
      #pragma unroll
      for (int k = 0; k < H; ++k)
        s = fmaf(sW2[hh * H + k], sSel[fp * 65 + k], s);
      g_U[(f * H + hh) * F + fp] = s;
    }
  } else {
    // c[fp] = bsel[fp] + sum_d b2flat[d] * Wsel[fp, d]
    int fp = t >> 3;        // 0..31
    int part = t & 7;       // 8 partials of 256
    const float* ser = Wsel + fp * (F * H);
    float s = 0.f;
    for (int d = part * 256; d < part * 256 + 256; ++d) s = fmaf(b2[d], ser[d], s);
    s += __shfl_xor(s, 1);
    s += __shfl_xor(s, 2);
    s += __shfl_xor(s, 4);
    if (part == 0) g_c[fp] = s + bsel[fp];
  }
}

__global__ void __launch_bounds__(512)
vsn_main(const float* __restrict__ x, const float* __restrict__ W1,
         const float* __restrict__ b1, const float* __restrict__ W2,
         const float* __restrict__ b2, float* __restrict__ out) {
  __shared__ float lacc[TOK_PER_BLK * 33];  // logits accum / softmax weights
  __shared__ float oacc[TOK_PER_BLK * 65];  // output accum

  const int tid  = threadIdx.x;
  const int lane = tid & 63;          // lane = local token
  const int wv   = tid >> 6;          // 0..7
  const int fbase = __builtin_amdgcn_readfirstlane(wv * FPW);
  const int tok  = blockIdx.x * TOK_PER_BLK + lane;
  const float* xrow = x + tok * F;

  // init accumulators: lacc <- c[j], oacc <- 0
  for (int i = tid; i < TOK_PER_BLK * F; i += 512)
    lacc[(i >> 5) * 33 + (i & 31)] = g_c[i & 31];
  for (int i = tid; i < TOK_PER_BLK * H; i += 512)
    oacc[(i >> 6) * 65 + (i & 63)] = 0.f;

  // per-lane x for this wave's 4 features
  float xv[FPW];
  #pragma unroll
  for (int i = 0; i < FPW; ++i) xv[i] = xrow[fbase + i];
  __syncthreads();

  // ---------- phase 1: logit partials via fused U ----------
  float lg[32];
  #pragma unroll
  for (int j = 0; j < 32; ++j) lg[j] = 0.f;

  #pragma unroll 1
  for (int i = 0; i < FPW; ++i) {
    const int f = fbase + i;
    const float xf = xv[i];
    const float* w1p = W1 + f * H;
    const float* b1p = b1 + f * H;
    const float* Up  = g_U + f * (H * F);
    #pragma unroll 2
    for (int hh = 0; hh < H; ++hh) {
      float h = fmaxf(fmaf(xf, w1p[hh], b1p[hh]), 0.f);
      #pragma unroll
      for (int j = 0; j < 32; ++j) lg[j] = fmaf(h, Up[hh * 32 + j], lg[j]);
    }
  }
  #pragma unroll
  for (int j = 0; j < 32; ++j) atomicAdd(&lacc[lane * 33 + j], lg[j]);
  __syncthreads();

  // per-lane softmax (wave 0; each lane owns its token's row), in place
  if (wv == 0) {
    float fl[32];
    #pragma unroll
    for (int j = 0; j < 32; ++j) fl[j] = lacc[lane * 33 + j];
    float m = fl[0];
    #pragma unroll
    for (int j = 1; j < 32; ++j) m = fmaxf(m, fl[j]);
    float z = 0.f;
    #pragma unroll
    for (int j = 0; j < 32; ++j) { fl[j] = __expf(fl[j] - m); z += fl[j]; }
    const float inv = 1.f / z;
    #pragma unroll
    for (int j = 0; j < 32; ++j) lacc[lane * 33 + j] = fl[j] * inv;
  }
  __syncthreads();

  // ---------- phase 2: out[k] partials ----------
  float acc[64];
  #pragma unroll
  for (int k = 0; k < 64; ++k) acc[k] = 0.f;

  #pragma unroll 1
  for (int i = 0; i < FPW; ++i) {
    const int f = fbase + i;
    const float xf = xv[i];
    const float wf = lacc[lane * 33 + f];
    const float* w1p = W1 + f * H;
    const float* b1p = b1 + f * H;
    const float* w2p = W2 + f * (H * H);
    #pragma unroll 1    // 64 uniform W2 floats/iter keeps SGPR in budget
    for (int hh = 0; hh < H; ++hh) {
      float g = fmaxf(fmaf(xf, w1p[hh], b1p[hh]), 0.f) * wf;
      #pragma unroll
      for (int k = 0; k < 64; ++k) acc[k] = fmaf(g, w2p[hh * H + k], acc[k]);
    }
    #pragma unroll
    for (int k = 0; k < 64; ++k) acc[k] = fmaf(wf, b2[f * H + k], acc[k]);
  }
  #pragma unroll
  for (int k = 0; k < 64; ++k) atomicAdd(&oacc[lane * 65 + k], acc[k]);
  __syncthreads();

  // coalesced fp32 store
  float* op = out + blockIdx.x * (TOK_PER_BLK * H);
  #pragma unroll
  for (int e = 0; e < 8; ++e) {
    int flat = e * 512 + tid;
    op[flat] = oacc[(flat >> 6) * 65 + (flat & 63)];
  }
}

extern "C" void kernel_launch(void* const* d_in, const int* in_sizes, int n_in,
                              void* d_out, int out_size, void* d_ws, size_t ws_size,
                              hipStream_t stream) {
  (void)in_sizes; (void)n_in; (void)out_size; (void)d_ws; (void)ws_size;
  const float* x    = (const float*)d_in[0];
  const float* W1   = (const float*)d_in[1];
  const float* b1   = (const float*)d_in[2];
  const float* W2   = (const float*)d_in[3];
  const float* b2   = (const float*)d_in[4];
  const float* Wsel = (const float*)d_in[5];
  const float* bsel = (const float*)d_in[6];
  float* out = (float*)d_out;

  vsn_pre<<<F + 1, 256, 0, stream>>>(W2, b2, Wsel, bsel);
  vsn_main<<<512, 512, 0, stream>>>(x, W1, b1, W2, b2, out);
}

// Round 9
// 118.554 us; speedup vs baseline: 2.9005x; 2.9005x over previous
//
#include <hip/hip_runtime.h>
#include <hip/hip_bf16.h>

// SimpleVSN: B=64, T=512, F=32, H=64. Inputs fp32, output fp32.
// MFMA-bf16 version.
//   U[f,hh,fp] = sum_k W2[f,hh,k]*Wsel[fp, f*64+k]; c[fp] = bsel + b2flat@Wsel^T
//   logits = c + sum_f h_f @ U_f          (GEMM1, K=2048)
//   out    = sum_f (w*h)_f @ W2_f + w@b2  (GEMM2, K=2048+32 pseudo-step)
// Per block: 64 tokens, 8 waves. mfma_f32_16x16x32_bf16; wave -> K-complete
// output tiles (GEMM1: tile (mi=wv>>1, n0=wv&1); GEMM2: (mi,n0)+(mi,n0+2))
// so NO cross-wave reduction. h recomputed for phase 2 with w folded in.
// hA: 64x64 bf16 LDS tile, XOR-swizzled (idx ^= (row&7)<<3), double-buffered.
// U/W2/b2 pre-swizzled to MFMA B-fragment order in bf16 by vsn_pre:
//   B[k=(l>>4)*8+j][n=ni*16+(l&15)] stored at [..][ks][ni][l][j] (16B/lane).
// A-fragment layout A[row=l&15][k=(l>>4)*8+j] per m97's ds_read_b128-verified
// contiguous-K pattern; C/D col=l&15,row=(l>>4)*4+r per m89/m91.

namespace {
constexpr int F = 32, H = 64, TOK = 64;
}

typedef __attribute__((ext_vector_type(8))) short bf16x8;
typedef __attribute__((ext_vector_type(4))) float f32x4;

__device__ short g_Ubf[F * 2 * 2 * 64 * 8];   // [f][ks][ni2][l][j]
__device__ short g_W2sw[F * 2 * 4 * 64 * 8];  // [f][ks][ni4][l][j]
__device__ short g_b2sw[4 * 64 * 8];          // [ni4][l][j]  (K=32 pseudo-step)
__device__ float g_c[F];

__device__ __forceinline__ short f2bf(float f) {
  union { __hip_bfloat16 b; short s; } u;
  u.b = __float2bfloat16(f);   // RNE
  return u.s;
}

// blocks 0..31: U[f] via LDS (sW2 @ sSel^T) -> bf16 swizzled; also W2sw[f].
// block 32: c[fp] and b2sw.
__global__ void __launch_bounds__(256)
vsn_pre(const float* __restrict__ W2, const float* __restrict__ b2,
        const float* __restrict__ Wsel, const float* __restrict__ bsel) {
  __shared__ float sW2[H * H];     // [hh][k]
  __shared__ float sSel[F * 65];   // [fp][k] padded
  const int f = blockIdx.x;
  const int t = threadIdx.x;
  if (f < F) {
    #pragma unroll
    for (int i = 0; i < 16; ++i) sW2[t + 256 * i] = W2[f * H * H + t + 256 * i];
    const int kk = t & 63;
    #pragma unroll
    for (int r = 0; r < 8; ++r) {
      int fp = (t >> 6) + 4 * r;
      sSel[fp * 65 + kk] = Wsel[fp * (F * H) + f * H + kk];
    }
    __syncthreads();
    // U[f][hh][fp] -> g_Ubf swizzled
    {
      const int fp = t & 31, hh0 = t >> 5;
      #pragma unroll
      for (int i = 0; i < 8; ++i) {
        int hh = hh0 * 8 + i;
        float s = 0.f;
        #pragma unroll
        for (int k = 0; k < H; ++k) s = fmaf(sW2[hh * H + k], sSel[fp * 65 + k], s);
        int ks = hh >> 5, j = hh & 7, lhi = (hh >> 3) & 3;
        int ni = fp >> 4, llo = fp & 15;
        g_Ubf[(((f * 2 + ks) * 2 + ni) * 64 + (lhi * 16 + llo)) * 8 + j] = f2bf(s);
      }
    }
    // W2sw[f]: coalesced 16B writes
    {
      const int l = t & 63, grp = t >> 6;
      #pragma unroll
      for (int rep = 0; rep < 2; ++rep) {
        int c = grp * 2 + rep;          // 0..7 = (ks, ni)
        int ks = c >> 2, ni = c & 3;
        bf16x8 v;
        #pragma unroll
        for (int j = 0; j < 8; ++j)
          v[j] = f2bf(sW2[(ks * 32 + ((l >> 4) << 3) + j) * H + ni * 16 + (l & 15)]);
        *reinterpret_cast<bf16x8*>(&g_W2sw[(((f * 2 + ks) * 4 + ni) * 64 + l) * 8]) = v;
      }
    }
  } else {
    // c[fp] = bsel[fp] + sum_d b2flat[d]*Wsel[fp,d]
    int fp = t >> 3, part = t & 7;
    const float* ser = Wsel + fp * (F * H);
    float s = 0.f;
    for (int d = part * 256; d < part * 256 + 256; ++d) s = fmaf(b2[d], ser[d], s);
    s += __shfl_xor(s, 1);
    s += __shfl_xor(s, 2);
    s += __shfl_xor(s, 4);
    if (part == 0) g_c[fp] = s + bsel[fp];
    // b2sw: B[k=f'][n=k_out] fragments
    {
      const int l = t & 63, ni = t >> 6;
      bf16x8 v;
      #pragma unroll
      for (int j = 0; j < 8; ++j)
        v[j] = f2bf(b2[(((l >> 4) << 3) + j) * H + ni * 16 + (l & 15)]);
      *reinterpret_cast<bf16x8*>(&g_b2sw[(ni * 64 + l) * 8]) = v;
    }
  }
}

__global__ void __launch_bounds__(512)
vsn_main(const float* __restrict__ x, const float* __restrict__ W1,
         const float* __restrict__ b1, float* __restrict__ out) {
  __shared__ short hAs[2 * TOK * H];   // swizzled bf16 h-tile, double-buffered
  __shared__ float sW1[F * H];
  __shared__ float sb1[F * H];
  __shared__ float sx[TOK * 33];       // x[t][f]
  __shared__ float lacc[TOK * 33];     // logits -> softmax weights

  const int tid = threadIdx.x;
  const int l   = tid & 63;
  const int wv  = tid >> 6;            // 0..7
  const int mi  = wv >> 1;             // M-tile 0..3
  const int n0  = wv & 1;              // GEMM1 ni; GEMM2 tiles n0, n0+2
  const int tokbase = blockIdx.x * TOK;

  for (int i = tid; i < F * H; i += 512) { sW1[i] = W1[i]; sb1[i] = b1[i]; }
  for (int i = tid; i < TOK * F; i += 512)
    sx[(i >> 5) * 33 + (i & 31)] = x[tokbase * F + i];

  f32x4 acc1;
  { float cv = g_c[n0 * 16 + (l & 15)]; acc1[0] = cv; acc1[1] = cv; acc1[2] = cv; acc1[3] = cv; }
  f32x4 acc2a = {0.f, 0.f, 0.f, 0.f}, acc2b = {0.f, 0.f, 0.f, 0.f};

  __syncthreads();

  const int hh0 = wv * 8;   // this wave's hh slice for h-compute (lane = token)

  auto computeH = [&](int f, int buf, bool scale) {
    const f32x4 w1a = *reinterpret_cast<const f32x4*>(&sW1[f * H + hh0]);
    const f32x4 w1b = *reinterpret_cast<const f32x4*>(&sW1[f * H + hh0 + 4]);
    const f32x4 b1a = *reinterpret_cast<const f32x4*>(&sb1[f * H + hh0]);
    const f32x4 b1b = *reinterpret_cast<const f32x4*>(&sb1[f * H + hh0 + 4]);
    const float xv = sx[l * 33 + f];
    const float wf = scale ? lacc[l * 33 + f] : 1.f;
    bf16x8 hv;
    #pragma unroll
    for (int j = 0; j < 4; ++j) {
      float h0 = fmaxf(fmaf(xv, w1a[j], b1a[j]), 0.f);
      float h1 = fmaxf(fmaf(xv, w1b[j], b1b[j]), 0.f);
      if (scale) { h0 *= wf; h1 *= wf; }
      hv[j]     = f2bf(h0);
      hv[j + 4] = f2bf(h1);
    }
    // token row = l, cols hh0..hh0+8; XOR-swizzle keeps 16B runs intact
    *reinterpret_cast<bf16x8*>(
        &hAs[buf * (TOK * H) + ((l * 64 + hh0) ^ ((l & 7) << 3))]) = hv;
  };

  auto readA = [&](int buf, int ks) {
    const int row = mi * 16 + (l & 15);
    const int idx = (row * 64 + ks * 32 + ((l >> 4) << 3)) ^ ((row & 7) << 3);
    return *reinterpret_cast<const bf16x8*>(&hAs[buf * (TOK * H) + idx]);
  };

  // ---------------- phase 1: logits ----------------
  computeH(0, 0, false);
  __syncthreads();

  #pragma unroll 1
  for (int f = 0; f < F; ++f) {
    const short* bu = g_Ubf + (f * 4 + n0) * 512;
    bf16x8 bk0 = *reinterpret_cast<const bf16x8*>(bu + l * 8);
    bf16x8 bk1 = *reinterpret_cast<const bf16x8*>(bu + 2 * 512 + l * 8);
    if (f < F - 1) computeH(f + 1, (f + 1) & 1, false);
    bf16x8 a0 = readA(f & 1, 0);
    bf16x8 a1 = readA(f & 1, 1);
    acc1 = __builtin_amdgcn_mfma_f32_16x16x32_bf16(a0, bk0, acc1, 0, 0, 0);
    acc1 = __builtin_amdgcn_mfma_f32_16x16x32_bf16(a1, bk1, acc1, 0, 0, 0);
    __syncthreads();
  }

  // write logits tile: C layout col=l&15, row=(l>>4)*4+r
  #pragma unroll
  for (int r = 0; r < 4; ++r) {
    int t = mi * 16 + ((l >> 4) << 2) + r;
    lacc[t * 33 + n0 * 16 + (l & 15)] = acc1[r];
  }
  __syncthreads();

  if (wv == 0) {   // per-lane softmax, lane = token
    float fl[32]; float m = -3.0e38f;
    #pragma unroll
    for (int j = 0; j < 32; ++j) { fl[j] = lacc[l * 33 + j]; m = fmaxf(m, fl[j]); }
    float z = 0.f;
    #pragma unroll
    for (int j = 0; j < 32; ++j) { fl[j] = __expf(fl[j] - m); z += fl[j]; }
    float inv = 1.f / z;
    #pragma unroll
    for (int j = 0; j < 32; ++j) lacc[l * 33 + j] = fl[j] * inv;
  }
  __syncthreads();

  // ---------------- phase 2: out ----------------
  computeH(0, 0, true);
  __syncthreads();

  #pragma unroll 1
  for (int f = 0; f < F; ++f) {
    const short* bw = g_W2sw + f * 8 * 512;
    bf16x8 b00 = *reinterpret_cast<const bf16x8*>(bw + (n0)         * 512 + l * 8);
    bf16x8 b01 = *reinterpret_cast<const bf16x8*>(bw + (n0 + 2)     * 512 + l * 8);
    bf16x8 b10 = *reinterpret_cast<const bf16x8*>(bw + (4 + n0)     * 512 + l * 8);
    bf16x8 b11 = *reinterpret_cast<const bf16x8*>(bw + (4 + n0 + 2) * 512 + l * 8);
    if (f < F - 1) computeH(f + 1, (f + 1) & 1, true);
    bf16x8 a0 = readA(f & 1, 0);
    bf16x8 a1 = readA(f & 1, 1);
    acc2a = __builtin_amdgcn_mfma_f32_16x16x32_bf16(a0, b00, acc2a, 0, 0, 0);
    acc2b = __builtin_amdgcn_mfma_f32_16x16x32_bf16(a0, b01, acc2b, 0, 0, 0);
    acc2a = __builtin_amdgcn_mfma_f32_16x16x32_bf16(a1, b10, acc2a, 0, 0, 0);
    acc2b = __builtin_amdgcn_mfma_f32_16x16x32_bf16(a1, b11, acc2b, 0, 0, 0);
    __syncthreads();
  }

  // pseudo-K-step: out += w @ b2  (A = softmax weights, K=32)
  {
    bf16x8 aw;
    const int t = mi * 16 + (l & 15);
    #pragma unroll
    for (int j = 0; j < 8; ++j) aw[j] = f2bf(lacc[t * 33 + ((l >> 4) << 3) + j]);
    bf16x8 bb0 = *reinterpret_cast<const bf16x8*>(g_b2sw + (n0)     * 512 + l * 8);
    bf16x8 bb1 = *reinterpret_cast<const bf16x8*>(g_b2sw + (n0 + 2) * 512 + l * 8);
    acc2a = __builtin_amdgcn_mfma_f32_16x16x32_bf16(aw, bb0, acc2a, 0, 0, 0);
    acc2b = __builtin_amdgcn_mfma_f32_16x16x32_bf16(aw, bb1, acc2b, 0, 0, 0);
  }

  float* op = out + tokbase * H;
  #pragma unroll
  for (int r = 0; r < 4; ++r) {
    int t = mi * 16 + ((l >> 4) << 2) + r;
    op[t * H + n0 * 16 + (l & 15)]       = acc2a[r];
    op[t * H + (n0 + 2) * 16 + (l & 15)] = acc2b[r];
  }
}

extern "C" void kernel_launch(void* const* d_in, const int* in_sizes, int n_in,
                              void* d_out, int out_size, void* d_ws, size_t ws_size,
                              hipStream_t stream) {
  (void)in_sizes; (void)n_in; (void)out_size; (void)d_ws; (void)ws_size;
  const float* x    = (const float*)d_in[0];
  const float* W1   = (const float*)d_in[1];
  const float* b1   = (const float*)d_in[2];
  const float* W2   = (const float*)d_in[3];
  const float* b2   = (const float*)d_in[4];
  const float* Wsel = (const float*)d_in[5];
  const float* bsel = (const float*)d_in[6];
  float* out = (float*)d_out;

  vsn_pre<<<F + 1, 256, 0, stream>>>(W2, b2, Wsel, bsel);
  vsn_main<<<512, 512, 0, stream>>>(x, W1, b1, out);
}

// Round 11
// 111.872 us; speedup vs baseline: 3.0737x; 1.0597x over previous
//
#include <hip/hip_runtime.h>
#include <hip/hip_bf16.h>

// SimpleVSN: B=64, T=512, F=32, H=64. Inputs fp32, output fp32.
// MFMA-bf16, v4: barrier-free K-loops via K-split wave ownership.
//   U[f,hh,fp] = sum_k W2[f,hh,k]*Wsel[fp, f*64+k]; c[fp] = bsel + b2flat@Wsel^T
//   logits = c + sum_f h_f @ U_f          (GEMM1, K=2048)
//   out    = sum_f (w*h)_f @ W2_f + w@b2  (GEMM2, K=2048 + K=32 pseudo-step)
// Per block: 64 tokens, 8 waves = (mi 0..3, p 0..1). Lane l of wave (mi,p)
// computes ITS OWN A-fragment h[tok=mi*16+(l&15)][hh=p*32+(l>>4)*8+j] in
// registers (8 fma+relu+cvt) -> no LDS h-tile, no barriers inside the
// 32-iteration K-loops. Wave accumulates K-half p; one LDS merge per GEMM
// (p=0 writes, p=1 adds) completes the K-sum. 6 barriers total (was 64+).
// B-frags (U/W2/b2) pre-swizzled to MFMA B order by vsn_pre:
//   B[k=(l>>4)*8+j][n=ni*16+(l&15)] at [..][ks][ni][l][j] (16B/lane, coalesced).
// C/D layout col=l&15, row=(l>>4)*4+r (m89/m91-verified).

namespace {
constexpr int F = 32, H = 64, TOK = 64;
}

typedef __attribute__((ext_vector_type(8))) short bf16x8;
typedef __attribute__((ext_vector_type(4))) float f32x4;

__device__ short g_Ubf[F * 2 * 2 * 64 * 8];   // [f][ks][ni2][l][j]
__device__ short g_W2sw[F * 2 * 4 * 64 * 8];  // [f][ks][ni4][l][j]
__device__ short g_b2sw[4 * 64 * 8];          // [ni4][l][j]  (K=32 pseudo-step)
__device__ float g_c[F];

__device__ __forceinline__ short f2bf(float f) {
  union { __hip_bfloat16 b; short s; } u;
  u.b = __float2bfloat16(f);   // RNE
  return u.s;
}

// blocks 0..31: U[f] via LDS (sW2 @ sSel^T) -> bf16 swizzled; also W2sw[f].
// block 32: c[fp] and b2sw.  (unchanged from round 9 - verified working)
__global__ void __launch_bounds__(256)
vsn_pre(const float* __restrict__ W2, const float* __restrict__ b2,
        const float* __restrict__ Wsel, const float* __restrict__ bsel) {
  __shared__ float sW2[H * H];     // [hh][k]
  __shared__ float sSel[F * 65];   // [fp][k] padded
  const int f = blockIdx.x;
  const int t = threadIdx.x;
  if (f < F) {
    #pragma unroll
    for (int i = 0; i < 16; ++i) sW2[t + 256 * i] = W2[f * H * H + t + 256 * i];
    const int kk = t & 63;
    #pragma unroll
    for (int r = 0; r < 8; ++r) {
      int fp = (t >> 6) + 4 * r;
      sSel[fp * 65 + kk] = Wsel[fp * (F * H) + f * H + kk];
    }
    __syncthreads();
    {
      const int fp = t & 31, hh0 = t >> 5;
      #pragma unroll
      for (int i = 0; i < 8; ++i) {
        int hh = hh0 * 8 + i;
        float s = 0.f;
        #pragma unroll
        for (int k = 0; k < H; ++k) s = fmaf(sW2[hh * H + k], sSel[fp * 65 + k], s);
        int ks = hh >> 5, j = hh & 7, lhi = (hh >> 3) & 3;
        int ni = fp >> 4, llo = fp & 15;
        g_Ubf[(((f * 2 + ks) * 2 + ni) * 64 + (lhi * 16 + llo)) * 8 + j] = f2bf(s);
      }
    }
    {
      const int l = t & 63, grp = t >> 6;
      #pragma unroll
      for (int rep = 0; rep < 2; ++rep) {
        int c = grp * 2 + rep;          // 0..7 = (ks, ni)
        int ks = c >> 2, ni = c & 3;
        bf16x8 v;
        #pragma unroll
        for (int j = 0; j < 8; ++j)
          v[j] = f2bf(sW2[(ks * 32 + ((l >> 4) << 3) + j) * H + ni * 16 + (l & 15)]);
        *reinterpret_cast<bf16x8*>(&g_W2sw[(((f * 2 + ks) * 4 + ni) * 64 + l) * 8]) = v;
      }
    }
  } else {
    int fp = t >> 3, part = t & 7;
    const float* ser = Wsel + fp * (F * H);
    float s = 0.f;
    for (int d = part * 256; d < part * 256 + 256; ++d) s = fmaf(b2[d], ser[d], s);
    s += __shfl_xor(s, 1);
    s += __shfl_xor(s, 2);
    s += __shfl_xor(s, 4);
    if (part == 0) g_c[fp] = s + bsel[fp];
    {
      const int l = t & 63, ni = t >> 6;
      bf16x8 v;
      #pragma unroll
      for (int j = 0; j < 8; ++j)
        v[j] = f2bf(b2[(((l >> 4) << 3) + j) * H + ni * 16 + (l & 15)]);
      *reinterpret_cast<bf16x8*>(&g_b2sw[(ni * 64 + l) * 8]) = v;
    }
  }
}

__global__ void __launch_bounds__(512, 4)
vsn_main(const float* __restrict__ x, const float* __restrict__ W1,
         const float* __restrict__ b1, float* __restrict__ out) {
  __shared__ float sx[TOK * 33];    // x[t][f], stride 33 (conflict-free)
  __shared__ float sW1[F * H];
  __shared__ float sb1[F * H];
  __shared__ float lacc[TOK * 33];  // logit merge -> softmax weights
  __shared__ float omrg[TOK * 65];  // output merge

  const int tid = threadIdx.x;
  const int l   = tid & 63;
  const int wv  = tid >> 6;          // 0..7
  const int mi  = wv >> 1;           // M-tile 0..3
  const int p   = wv & 1;            // K-half 0..1
  const int l15 = l & 15;
  const int kg  = l >> 4;            // 0..3
  const int tokbase = blockIdx.x * TOK;
  const int row_tok = mi * 16 + l15; // this lane's A-row (token)
  const int hoff = p * 32 + kg * 8;  // this lane's hh base

  for (int i = tid; i < F * H; i += 512) { sW1[i] = W1[i]; sb1[i] = b1[i]; }
  for (int i = tid; i < TOK * F; i += 512)
    sx[(i >> 5) * 33 + (i & 31)] = x[tokbase * F + i];
  __syncthreads();   // B1

  // ---------------- phase 1: logits (no barriers in loop) ----------------
  f32x4 acc1[2] = {};
  #pragma unroll 2
  for (int f = 0; f < F; ++f) {
    const f32x4 w1a = *reinterpret_cast<const f32x4*>(&sW1[f * H + hoff]);
    const f32x4 w1b = *reinterpret_cast<const f32x4*>(&sW1[f * H + hoff + 4]);
    const f32x4 b1a = *reinterpret_cast<const f32x4*>(&sb1[f * H + hoff]);
    const f32x4 b1b = *reinterpret_cast<const f32x4*>(&sb1[f * H + hoff + 4]);
    const float xv = sx[row_tok * 33 + f];
    bf16x8 af;
    #pragma unroll
    for (int j = 0; j < 4; ++j) {
      af[j]     = f2bf(fmaxf(fmaf(xv, w1a[j], b1a[j]), 0.f));
      af[j + 4] = f2bf(fmaxf(fmaf(xv, w1b[j], b1b[j]), 0.f));
    }
    const short* bu = g_Ubf + ((f * 2 + p) * 2) * 512;   // [f][ks=p][ni][l][j]
    bf16x8 bk0 = *reinterpret_cast<const bf16x8*>(bu + l * 8);
    bf16x8 bk1 = *reinterpret_cast<const bf16x8*>(bu + 512 + l * 8);
    acc1[0] = __builtin_amdgcn_mfma_f32_16x16x32_bf16(af, bk0, acc1[0], 0, 0, 0);
    acc1[1] = __builtin_amdgcn_mfma_f32_16x16x32_bf16(af, bk1, acc1[1], 0, 0, 0);
  }

  // K-merge: p=0 writes (+c), p=1 adds.  C layout: col=l15, row=kg*4+r.
  if (p == 0) {
    #pragma unroll
    for (int ni = 0; ni < 2; ++ni)
      #pragma unroll
      for (int r = 0; r < 4; ++r)
        lacc[(mi * 16 + kg * 4 + r) * 33 + ni * 16 + l15] =
            g_c[ni * 16 + l15] + acc1[ni][r];
  }
  __syncthreads();   // B2
  if (p == 1) {
    #pragma unroll
    for (int ni = 0; ni < 2; ++ni)
      #pragma unroll
      for (int r = 0; r < 4; ++r)
        lacc[(mi * 16 + kg * 4 + r) * 33 + ni * 16 + l15] += acc1[ni][r];
  }
  __syncthreads();   // B3

  // softmax: 4 waves (p==0) in parallel, lanes 0..15, token = mi*16+l
  if (p == 0 && l < 16) {
    const int t = mi * 16 + l;
    float fl[32]; float m = -3.0e38f;
    #pragma unroll
    for (int j = 0; j < 32; ++j) { fl[j] = lacc[t * 33 + j]; m = fmaxf(m, fl[j]); }
    float z = 0.f;
    #pragma unroll
    for (int j = 0; j < 32; ++j) { fl[j] = __expf(fl[j] - m); z += fl[j]; }
    const float inv = 1.f / z;
    #pragma unroll
    for (int j = 0; j < 32; ++j) lacc[t * 33 + j] = fl[j] * inv;
  }
  __syncthreads();   // B4

  // ---------------- phase 2: out (no barriers in loop) ----------------
  f32x4 acc2[4] = {};
  #pragma unroll 2
  for (int f = 0; f < F; ++f) {
    const f32x4 w1a = *reinterpret_cast<const f32x4*>(&sW1[f * H + hoff]);
    const f32x4 w1b = *reinterpret_cast<const f32x4*>(&sW1[f * H + hoff + 4]);
    const f32x4 b1a = *reinterpret_cast<const f32x4*>(&sb1[f * H + hoff]);
    const f32x4 b1b = *reinterpret_cast<const f32x4*>(&sb1[f * H + hoff + 4]);
    const float xv = sx[row_tok * 33 + f];
    const float wf = lacc[row_tok * 33 + f];
    bf16x8 af;
    #pragma unroll
    for (int j = 0; j < 4; ++j) {
      af[j]     = f2bf(fmaxf(fmaf(xv, w1a[j], b1a[j]), 0.f) * wf);
      af[j + 4] = f2bf(fmaxf(fmaf(xv, w1b[j], b1b[j]), 0.f) * wf);
    }
    const short* bw = g_W2sw + ((f * 2 + p) * 4) * 512;  // [f][ks=p][ni][l][j]
    #pragma unroll
    for (int ni = 0; ni < 4; ++ni) {
      bf16x8 bb = *reinterpret_cast<const bf16x8*>(bw + ni * 512 + l * 8);
      acc2[ni] = __builtin_amdgcn_mfma_f32_16x16x32_bf16(af, bb, acc2[ni], 0, 0, 0);
    }
  }

  // b2 pseudo-K-step (K=32): A[t][f'] = w; only p=0 waves carry it.
  if (p == 0) {
    bf16x8 aw;
    #pragma unroll
    for (int j = 0; j < 8; ++j)
      aw[j] = f2bf(lacc[row_tok * 33 + kg * 8 + j]);
    #pragma unroll
    for (int ni = 0; ni < 4; ++ni) {
      bf16x8 bb = *reinterpret_cast<const bf16x8*>(g_b2sw + ni * 512 + l * 8);
      acc2[ni] = __builtin_amdgcn_mfma_f32_16x16x32_bf16(aw, bb, acc2[ni], 0, 0, 0);
    }
  }

  // K-merge for out
  if (p == 0) {
    #pragma unroll
    for (int ni = 0; ni < 4; ++ni)
      #pragma unroll
      for (int r = 0; r < 4; ++r)
        omrg[(mi * 16 + kg * 4 + r) * 65 + ni * 16 + l15] = acc2[ni][r];
  }
  __syncthreads();   // B5
  if (p == 1) {
    #pragma unroll
    for (int ni = 0; ni < 4; ++ni)
      #pragma unroll
      for (int r = 0; r < 4; ++r)
        omrg[(mi * 16 + kg * 4 + r) * 65 + ni * 16 + l15] += acc2[ni][r];
  }
  __syncthreads();   // B6

  // coalesced store
  float* op = out + tokbase * H;
  #pragma unroll
  for (int e = 0; e < 8; ++e) {
    int flat = e * 512 + tid;
    op[flat] = omrg[(flat >> 6) * 65 + (flat & 63)];
  }
}

extern "C" void kernel_launch(void* const* d_in, const int* in_sizes, int n_in,
                              void* d_out, int out_size, void* d_ws, size_t ws_size,
                              hipStream_t stream) {
  (void)in_sizes; (void)n_in; (void)out_size; (void)d_ws; (void)ws_size;
  const float* x    = (const float*)d_in[0];
  const float* W1   = (const float*)d_in[1];
  const float* b1   = (const float*)d_in[2];
  const float* W2   = (const float*)d_in[3];
  const float* b2   = (const float*)d_in[4];
  const float* Wsel = (const float*)d_in[5];
  const float* bsel = (const float*)d_in[6];
  float* out = (float*)d_out;

  vsn_pre<<<F + 1, 256, 0, stream>>>(W2, b2, Wsel, bsel);
  vsn_main<<<512, 512, 0, stream>>>(x, W1, b1, out);
}